// Round 16
// baseline (124.143 us; speedup 1.0000x reference)
//
#include <hip/hip_runtime.h>
#include <cmath>

#define BATCH 8
#define SEQ   2048
#define NEMB  2048
#define HD    128
#define NROWS (BATCH * SEQ)   // 16384

typedef __bf16 v8bf __attribute__((ext_vector_type(8)));
typedef float  f32x4 __attribute__((ext_vector_type(4)));

union U8 { v8bf v; __bf16 b[8]; unsigned short e[8]; };
union F4 { f32x4 v; float f[4]; };

__device__ inline void async16(void* lds, const void* g) {
  __builtin_amdgcn_global_load_lds(
      (const __attribute__((address_space(1))) unsigned int*)g,
      (__attribute__((address_space(3))) unsigned int*)lds, 16, 0, 0);
}

__device__ inline v8bf cvt8(float4 a, float4 b) {
  U8 u;
  u.b[0] = (__bf16)a.x; u.b[1] = (__bf16)a.y; u.b[2] = (__bf16)a.z; u.b[3] = (__bf16)a.w;
  u.b[4] = (__bf16)b.x; u.b[5] = (__bf16)b.y; u.b[6] = (__bf16)b.z; u.b[7] = (__bf16)b.w;
  return u.v;
}

// ---------------- W fp32 -> bf16, MFMA-B-fragment packed ----------------
// unit u = nf_global*64 + tt*2 + kk   (nf_global = p*8+nf, 1KB units)
// elem j of (u,lane): W[p][nf*16 + (lane&15)][tt*64 + kk*32 + (lane>>4)*8 + j]
__global__ __launch_bounds__(256) void wpack_kernel(
    const float* __restrict__ Wq, const float* __restrict__ Wk,
    const float* __restrict__ Wv, __bf16* __restrict__ wp) {
  const int g = blockIdx.x * 256 + threadIdx.x;   // 384 blocks
  const int lane = g & 63;
  const int u = g >> 6;              // 0..1535
  const int kk = u & 1;
  const int tt = (u >> 1) & 31;
  const int nf = (u >> 6) & 7;
  const int p  = u >> 9;
  const float* __restrict__ W = p == 0 ? Wq : p == 1 ? Wk : Wv;
  const int row = nf * 16 + (lane & 15);
  const int k   = tt * 64 + kk * 32 + (lane >> 4) * 8;
  const float4* s = (const float4*)(W + (size_t)row * NEMB + k);
  float4 f0 = s[0], f1 = s[1];
  *(v8bf*)(wp + (size_t)g * 8) = cvt8(f0, f1);
}

// ---------------- Fused QKV projection, minimal-DMA ----------------
// One block per 64-row x-panel computes all 3 projections (64x384).
// 512 thr / 8 waves (2m x 4n); wave owns 32x96 (2x6 frags).
// DMA = A ONLY: fp32 [64][64] (16 KB/step) double-buffered -> total
// 512 KB/CU through the LDS-DMA path. B frags come from fragment-packed
// W (1.5 MB, L2-resident) straight to REGISTERS (normal vector path).
// r13 sync skeleton with counted vmcnt(14) (2 A-DMA + 12 B loads/step).
__global__ __launch_bounds__(512) void qkv_fused_kernel(
    const float* __restrict__ x, const __bf16* __restrict__ Wp,
    const float* __restrict__ bq, const float* __restrict__ bk,
    const float* __restrict__ bv,
    __bf16* __restrict__ Qb, __bf16* __restrict__ Kb, __bf16* __restrict__ Vb)
{
  const int bid0 = blockIdx.x;
  const int mt = ((bid0 & 7) << 5) + (bid0 >> 3);   // 256 % 8 == 0, chunk 32
  const int m0 = mt * 64;

  __shared__ float Asm[2][64 * 64];   // 32 KB total

  const int t = threadIdx.x, lane = t & 63, w = t >> 6;
  const int wm = w >> 2, wn4 = w & 3;       // wave: rows wm*32.., cols wn4*96..
  const int hi = lane >> 4, lo = lane & 15;

  // A staging: 16 chunks of 1KB (4 rows x 256B); 2 chunks/wave
  const float* pa[2];
  int laOff[2];
#pragma unroll
  for (int i = 0; i < 2; ++i) {
    const int j = w * 2 + i;
    const int r = j * 4 + (lane >> 4);
    const int c = (lane & 15) ^ (r & 7);
    pa[i] = x + (size_t)(m0 + r) * NEMB + c * 4;
    laOff[i] = j * 1024;
  }

  // B fragment base (per-lane)
  const __bf16* bb = Wp + lane * 8;

  f32x4 acc[2][6];
  const f32x4 fz = {0.f, 0.f, 0.f, 0.f};
#pragma unroll
  for (int m = 0; m < 2; ++m)
#pragma unroll
    for (int n = 0; n < 6; ++n) acc[m][n] = fz;

  v8bf B0[6][2], B1[6][2];
  auto LOADB = [&](v8bf (&B)[6][2], int tt) {
#pragma unroll
    for (int n = 0; n < 6; ++n)
#pragma unroll
      for (int kk = 0; kk < 2; ++kk)
        B[n][kk] = *(const v8bf*)(bb + (size_t)((wn4 * 6 + n) * 64 + tt * 2 + kk) * 512);
  };
  auto STAGE_A = [&](int tt, int buf) {
    const int k0 = tt * 64;
    char* base = (char*)&Asm[buf][0];
#pragma unroll
    for (int i = 0; i < 2; ++i) async16(base + laOff[i], pa[i] + k0);
  };
  auto COMPUTE = [&](int buf, v8bf (&B)[6][2]) {
    const char* Ab = (const char*)&Asm[buf][0];
#pragma unroll
    for (int kk = 0; kk < 2; ++kk) {
      v8bf a[2];
#pragma unroll
      for (int m = 0; m < 2; ++m) {
        const int r = wm * 32 + m * 16 + lo;
        const int s = kk * 8 + hi * 2;
        const char* rowp = Ab + r * 256;
        F4 a0, a1;
        a0.v = *(const f32x4*)(rowp + (((s)     ^ (r & 7)) << 4));
        a1.v = *(const f32x4*)(rowp + (((s + 1) ^ (r & 7)) << 4));
        U8 u;
#pragma unroll
        for (int q = 0; q < 4; ++q) {
          u.b[q]     = (__bf16)a0.f[q];
          u.b[q + 4] = (__bf16)a1.f[q];
        }
        a[m] = u.v;
      }
#pragma unroll
      for (int m = 0; m < 2; ++m)
#pragma unroll
        for (int n = 0; n < 6; ++n)
          acc[m][n] = __builtin_amdgcn_mfma_f32_16x16x32_bf16(a[m], B[n][kk], acc[m][n], 0, 0, 0);
    }
  };

  const int NT = NEMB / 64;  // 32 (even)
  STAGE_A(0, 0);
  LOADB(B0, 0);
  for (int tt = 0; tt < NT; tt += 2) {
    // step tt: compute buf0/B0, prefetch tt+1 -> buf1/B1
    __builtin_amdgcn_s_barrier();           // compute(tt-1) [buf1] done
    STAGE_A(tt + 1, 1);
    LOADB(B1, tt + 1);
    asm volatile("s_waitcnt vmcnt(14)" ::: "memory");  // step-tt A-DMA + B landed
    __builtin_amdgcn_s_barrier();           // all waves' A(tt) resident
    COMPUTE(0, B0);
    // step tt+1: compute buf1/B1, prefetch tt+2 -> buf0/B0
    __builtin_amdgcn_s_barrier();           // compute(tt) [buf0] done
    if (tt + 2 < NT) {
      STAGE_A(tt + 2, 0);
      LOADB(B0, tt + 2);
      asm volatile("s_waitcnt vmcnt(14)" ::: "memory");
    } else {
      asm volatile("s_waitcnt vmcnt(0)" ::: "memory");
    }
    __builtin_amdgcn_s_barrier();
    COMPUTE(1, B1);
  }

  // epilogue: per-frag projection select (16-col frags never cross proj edge)
#pragma unroll
  for (int n = 0; n < 6; ++n) {
    const int rrb = wn4 * 96 + n * 16;      // 0..368, multiple of 16
    const int pj = rrb >> 7;
    const int col = (rrb & 127) + lo;
    __bf16* __restrict__ Out = pj == 0 ? Qb : pj == 1 ? Kb : Vb;
    const float* __restrict__ bias = pj == 0 ? bq : pj == 1 ? bk : bv;
    const float bi = bias[col];
#pragma unroll
    for (int m = 0; m < 2; ++m) {
#pragma unroll
      for (int r = 0; r < 4; ++r) {
        const int row = m0 + wm * 32 + m * 16 + hi * 4 + r;
        Out[(size_t)row * HD + col] = (__bf16)(acc[m][n][r] + bi);
      }
    }
  }
}

// ---------------- Flash attention, split-KV x4 ----------------
// grid: 8 batches * 32 q-tiles * 4 kv-chunks = 1024 blocks, 256 thr.
__global__ __launch_bounds__(256) void attn_kernel(
    const __bf16* __restrict__ Qb, const __bf16* __restrict__ Kb,
    const __bf16* __restrict__ Vb, __bf16* __restrict__ Opart,
    float* __restrict__ Ml)
{
  const int bid0 = blockIdx.x;
  const int bid = ((bid0 & 7) << 7) + (bid0 >> 3);   // one batch per XCD
  const int b = bid >> 7;
  const int q = bid & 127;
  const int qt = q >> 2;
  const int s  = q & 3;
  const int q0 = qt * 64;
  const int kv_beg = (s * (qt + 1)) >> 2;
  const int kv_end = ((s + 1) * (qt + 1)) >> 2;
  const int nst = kv_end - kv_beg;

  const int t = threadIdx.x, lane = t & 63, w = t >> 6;
  const int hi = lane >> 4, lo = lane & 15;

  __shared__ __bf16 Ksm[2][64 * 128];   // [key][d], 256B rows, swizzled
  __shared__ __bf16 Vtsm[2][128 * 64];  // [d][key], 128B rows, swizzled
  __shared__ __bf16 Psm[4][16 * 64];    // per-wave P, swizzled

  v8bf aQ[4];
  {
    const __bf16* qp = Qb + ((size_t)(b * SEQ + q0 + w * 16 + lo)) * HD + hi * 8;
#pragma unroll
    for (int kk = 0; kk < 4; ++kk) aQ[kk] = *(const v8bf*)(qp + kk * 32);
  }

  const __bf16* kga[4];
#pragma unroll
  for (int i = 0; i < 4; ++i) {
    const int r = (w * 4 + i) * 4 + (lane >> 4);   // key row 0..63
    const int c = (lane & 15) ^ (r & 7);           // 16B chunk within 256B row
    kga[i] = Kb + ((size_t)(b * SEQ) + r) * HD + c * 8;
  }

  const int keyg = t >> 4, dg = t & 15;   // keys keyg*4.., d-cols dg*8..
  U8 vv[4];

  f32x4 accO[8];
  const f32x4 fz = {0.f, 0.f, 0.f, 0.f};
#pragma unroll
  for (int n = 0; n < 8; ++n) accO[n] = fz;
  float m_s[4], l_s[4];
#pragma unroll
  for (int r = 0; r < 4; ++r) { m_s[r] = -INFINITY; l_s[r] = 0.f; }

  const float scale = 0.022097086912079608f;  // 1/sqrt(2048)

  if (nst > 0) {
    auto STAGE_K = [&](int kv, int buf) {
      const size_t off = (size_t)kv * 64 * HD;
      char* kb = (char*)&Ksm[buf][0];
#pragma unroll
      for (int i = 0; i < 4; ++i) async16(kb + (w * 4 + i) * 1024, kga[i] + off);
    };
    auto LOAD_V = [&](int kv) {
      const __bf16* vp = Vb + ((size_t)(b * SEQ + kv * 64 + keyg * 4)) * HD + dg * 8;
#pragma unroll
      for (int j = 0; j < 4; ++j) vv[j].v = *(const v8bf*)(vp + (size_t)j * HD);
    };
    auto WRITE_VT = [&](int buf) {
      char* vb2 = (char*)&Vtsm[buf][0];
#pragma unroll
      for (int dd = 0; dd < 8; ++dd) {
        const int d = (dd + dg) & 7;               // rotation: row&7 spans lanes
        ushort4 pk = make_ushort4(vv[0].e[d], vv[1].e[d], vv[2].e[d], vv[3].e[d]);
        const int row = dg * 8 + d;
        *(ushort4*)(vb2 + row * 128 + ((keyg * 8) ^ ((row & 7) << 4))) = pk;
      }
    };

    STAGE_K(kv_beg, 0);
    LOAD_V(kv_beg);
    WRITE_VT(0);
    __syncthreads();   // K DMA drained + Vt visible

    for (int t2 = 0; t2 < nst; ++t2) {
      const int kv = kv_beg + t2;
      const int cur = t2 & 1;
      const bool more = (t2 + 1 < nst);
      if (more) { STAGE_K(kv + 1, cur ^ 1); LOAD_V(kv + 1); }

      // S = Q K^T
      f32x4 accS[4];
#pragma unroll
      for (int n = 0; n < 4; ++n) accS[n] = fz;
      const char* ksm = (const char*)&Ksm[cur][0];
#pragma unroll
      for (int kk = 0; kk < 4; ++kk) {
        const int cb = kk * 64 + hi * 16;
        v8bf bk[4];
#pragma unroll
        for (int n = 0; n < 4; ++n) {
          const int r = n * 16 + lo;
          bk[n] = *(const v8bf*)(ksm + r * 256 + (cb ^ ((r & 7) << 4)));
        }
#pragma unroll
        for (int n = 0; n < 4; ++n)
          accS[n] = __builtin_amdgcn_mfma_f32_16x16x32_bf16(aQ[kk], bk[n], accS[n], 0, 0, 0);
      }

      float sv[4][4];
      const bool diag = (kv == qt);
#pragma unroll
      for (int n = 0; n < 4; ++n)
#pragma unroll
        for (int r = 0; r < 4; ++r) {
          float v = accS[n][r] * scale;
          if (diag) {
            const int key = kv * 64 + n * 16 + lo;
            const int qr = q0 + w * 16 + hi * 4 + r;
            if (key > qr) v = -INFINITY;
          }
          sv[n][r] = v;
        }

      float mx[4];
#pragma unroll
      for (int r = 0; r < 4; ++r) {
        mx[r] = fmaxf(fmaxf(sv[0][r], sv[1][r]), fmaxf(sv[2][r], sv[3][r]));
#pragma unroll
        for (int off = 1; off < 16; off <<= 1)
          mx[r] = fmaxf(mx[r], __shfl_xor(mx[r], off));
      }
      float corr[4], p[4][4], rs[4];
#pragma unroll
      for (int r = 0; r < 4; ++r) {
        const float mnew = fmaxf(m_s[r], mx[r]);
        corr[r] = __expf(m_s[r] - mnew);
        m_s[r] = mnew;
        rs[r] = 0.f;
      }
#pragma unroll
      for (int n = 0; n < 4; ++n)
#pragma unroll
        for (int r = 0; r < 4; ++r) {
          p[n][r] = __expf(sv[n][r] - m_s[r]);
          rs[r] += p[n][r];
        }
#pragma unroll
      for (int r = 0; r < 4; ++r) {
#pragma unroll
        for (int off = 1; off < 16; off <<= 1) rs[r] += __shfl_xor(rs[r], off);
        l_s[r] = l_s[r] * corr[r] + rs[r];
      }
#pragma unroll
      for (int n = 0; n < 8; ++n)
#pragma unroll
        for (int r = 0; r < 4; ++r) accO[n][r] *= corr[r];

#pragma unroll
      for (int n = 0; n < 4; ++n)
#pragma unroll
        for (int r = 0; r < 4; ++r) {
          const int row = hi * 4 + r;
          __bf16 h = (__bf16)p[n][r];
          *(unsigned short*)((char*)&Psm[w][0] + row * 128 +
                             (((n * 16 + lo) * 2) ^ ((row & 7) << 4))) =
              __builtin_bit_cast(unsigned short, h);
        }

      if (more) WRITE_VT(cur ^ 1);

      const char* vsm = (const char*)&Vtsm[cur][0];
#pragma unroll
      for (int k2 = 0; k2 < 2; ++k2) {
        const int cb = k2 * 64 + hi * 16;
        const v8bf aP = *(const v8bf*)((const char*)&Psm[w][0] + lo * 128 + (cb ^ ((lo & 7) << 4)));
#pragma unroll
        for (int n = 0; n < 8; ++n) {
          const int r = n * 16 + lo;
          const v8bf bv = *(const v8bf*)(vsm + r * 128 + (cb ^ ((r & 7) << 4)));
          accO[n] = __builtin_amdgcn_mfma_f32_16x16x32_bf16(aP, bv, accO[n], 0, 0, 0);
        }
      }
      if (more) __syncthreads();
    }
  }

  // store partials: unnormalized O (bf16), m, l
#pragma unroll
  for (int r = 0; r < 4; ++r) {
    const int qr = q0 + w * 16 + hi * 4 + r;
    __bf16* op = Opart + ((size_t)s * NROWS + b * SEQ + qr) * HD + lo;
#pragma unroll
    for (int n = 0; n < 8; ++n) op[n * 16] = (__bf16)accO[n][r];
    if (lo == 0) {
      float* mlp = Ml + ((size_t)s * NROWS + b * SEQ + qr) * 2;
      mlp[0] = m_s[r];
      mlp[1] = l_s[r];
    }
  }
}

// ---------------- combine the four KV-chunk partials ----------------
__global__ __launch_bounds__(256) void combine_kernel(
    const __bf16* __restrict__ Opart, const float* __restrict__ Ml,
    float* __restrict__ out)
{
  const int idx = blockIdx.x * 256 + threadIdx.x;  // 0..65535
  const int row = idx >> 2, ch = idx & 3;          // 32-col chunk
  float m[4], l[4];
#pragma unroll
  for (int s = 0; s < 4; ++s) {
    const float* mlp = Ml + ((size_t)s * NROWS + row) * 2;
    m[s] = mlp[0];
    l[s] = mlp[1];
  }
  const float M = fmaxf(fmaxf(m[0], m[1]), fmaxf(m[2], m[3]));
  float e[4], denom = 0.f;
#pragma unroll
  for (int s = 0; s < 4; ++s) { e[s] = __expf(m[s] - M); denom += l[s] * e[s]; }
  const float inv = 1.f / denom;

  float* po = out + (size_t)row * HD + ch * 32;
#pragma unroll
  for (int j = 0; j < 4; ++j) {     // 4 groups of 8 cols
    float sum[8];
#pragma unroll
    for (int q2 = 0; q2 < 8; ++q2) sum[q2] = 0.f;
#pragma unroll
    for (int s = 0; s < 4; ++s) {
      U8 o;
      o.v = *(const v8bf*)(Opart + ((size_t)s * NROWS + row) * HD + ch * 32 + j * 8);
#pragma unroll
      for (int q2 = 0; q2 < 8; ++q2) sum[q2] += (float)o.b[q2] * e[s];
    }
#pragma unroll
    for (int q2 = 0; q2 < 8; ++q2) po[j * 8 + q2] = sum[q2] * inv;
  }
}

extern "C" void kernel_launch(void* const* d_in, const int* in_sizes, int n_in,
                              void* d_out, int out_size, void* d_ws, size_t ws_size,
                              hipStream_t stream) {
  const float* x  = (const float*)d_in[0];
  const float* Wq = (const float*)d_in[1];
  const float* bq = (const float*)d_in[2];
  const float* Wk = (const float*)d_in[3];
  const float* bk = (const float*)d_in[4];
  const float* Wv = (const float*)d_in[5];
  const float* bv = (const float*)d_in[6];
  float* out = (float*)d_out;

  // workspace (~30 MiB)
  __bf16* Qb = (__bf16*)d_ws;                        // 16384x128 bf16 each
  __bf16* Kb = Qb + (size_t)NROWS * HD;
  __bf16* Vb = Kb + (size_t)NROWS * HD;
  __bf16* Wp = Vb + (size_t)NROWS * HD;              // 1536 x 512 bf16 = 1.5 MB
  __bf16* Opart = Wp + (size_t)1536 * 512;           // 4 x 16384 x 128 bf16
  float*  Ml = (float*)(Opart + (size_t)4 * NROWS * HD);  // 4 x 16384 x 2 fp32

  wpack_kernel<<<dim3(384), dim3(256), 0, stream>>>(Wq, Wk, Wv, Wp);
  qkv_fused_kernel<<<dim3(256), dim3(512), 0, stream>>>(
      x, Wp, bq, bk, bv, Qb, Kb, Vb);
  attn_kernel<<<dim3(BATCH * 32 * 4), dim3(256), 0, stream>>>(Qb, Kb, Vb, Opart, Ml);
  combine_kernel<<<dim3(NROWS * 4 / 256), dim3(256), 0, stream>>>(Opart, Ml, out);
}

// Round 17
// 123.439 us; speedup vs baseline: 1.0057x; 1.0057x over previous
//
#include <hip/hip_runtime.h>
#include <cmath>

#define BATCH 8
#define SEQ   2048
#define NEMB  2048
#define HD    128
#define NROWS (BATCH * SEQ)   // 16384

typedef __bf16 v8bf __attribute__((ext_vector_type(8)));
typedef float  f32x4 __attribute__((ext_vector_type(4)));

union U8 { v8bf v; __bf16 b[8]; unsigned short e[8]; };
union F4 { f32x4 v; float f[4]; };

__device__ inline void async16(void* lds, const void* g) {
  __builtin_amdgcn_global_load_lds(
      (const __attribute__((address_space(1))) unsigned int*)g,
      (__attribute__((address_space(3))) unsigned int*)lds, 16, 0, 0);
}

__device__ inline v8bf cvt8(float4 a, float4 b) {
  U8 u;
  u.b[0] = (__bf16)a.x; u.b[1] = (__bf16)a.y; u.b[2] = (__bf16)a.z; u.b[3] = (__bf16)a.w;
  u.b[4] = (__bf16)b.x; u.b[5] = (__bf16)b.y; u.b[6] = (__bf16)b.z; u.b[7] = (__bf16)b.w;
  return u.v;
}

// ---------------- W fp32 -> bf16, MFMA-B-fragment packed ----------------
__global__ __launch_bounds__(256) void wpack_kernel(
    const float* __restrict__ Wq, const float* __restrict__ Wk,
    const float* __restrict__ Wv, __bf16* __restrict__ wp) {
  const int g = blockIdx.x * 256 + threadIdx.x;   // 384 blocks
  const int lane = g & 63;
  const int u = g >> 6;              // 0..1535
  const int kk = u & 1;
  const int tt = (u >> 1) & 31;
  const int nf = (u >> 6) & 7;
  const int p  = u >> 9;
  const float* __restrict__ W = p == 0 ? Wq : p == 1 ? Wk : Wv;
  const int row = nf * 16 + (lane & 15);
  const int k   = tt * 64 + kk * 32 + (lane >> 4) * 8;
  const float4* s = (const float4*)(W + (size_t)row * NEMB + k);
  float4 f0 = s[0], f1 = s[1];
  *(v8bf*)(wp + (size_t)g * 8) = cvt8(f0, f1);
}

// ---------------- Fused QKV projection: barrier-free, wave-private -------
// One block per 64-row x-panel, 512 thr / 8 waves (2m x 4n); wave = 32x96.
// Each wave DMAs its OWN private A strip (32x64 fp32, 8 KB, dbuf) and loads
// its own B frags from L2-resident Wp to regs. ZERO inter-wave sharing ->
// ZERO barriers; waves self-pace on counted vmcnt(20) and drift to fill
// each other's load stalls (m114 mechanism, in-block).
__global__ __launch_bounds__(512, 2) void qkv_fused_kernel(
    const float* __restrict__ x, const __bf16* __restrict__ Wp,
    const float* __restrict__ bq, const float* __restrict__ bk,
    const float* __restrict__ bv,
    __bf16* __restrict__ Qb, __bf16* __restrict__ Kb, __bf16* __restrict__ Vb)
{
  const int bid0 = blockIdx.x;
  const int mt = ((bid0 & 7) << 5) + (bid0 >> 3);   // 256 % 8 == 0, chunk 32
  const int m0 = mt * 64;

  __shared__ char smem[131072];   // 8 waves x 2 bufs x 8 KB

  const int t = threadIdx.x, lane = t & 63, w = t >> 6;
  const int wm = w >> 2, wn4 = w & 3;       // wave: rows wm*32.., cols wn4*96..
  const int hi = lane >> 4, lo = lane & 15;

  char* const Abuf0 = smem + w * 16384;
  char* const Abuf1 = Abuf0 + 8192;

  // A staging: 8 chunks of 1KB (4 rows x 256B) covering the wave's 32 rows
  const float* pa[8];
#pragma unroll
  for (int i = 0; i < 8; ++i) {
    const int rl = i * 4 + (lane >> 4);            // row in strip, 0..31
    const int c = (lane & 15) ^ (rl & 7);          // inverse swizzle
    pa[i] = x + (size_t)(m0 + wm * 32 + rl) * NEMB + c * 4;
  }

  // B fragment base (per-lane)
  const __bf16* bb = Wp + lane * 8;

  f32x4 acc[2][6];
  const f32x4 fz = {0.f, 0.f, 0.f, 0.f};
#pragma unroll
  for (int m = 0; m < 2; ++m)
#pragma unroll
    for (int n = 0; n < 6; ++n) acc[m][n] = fz;

  v8bf B0[6][2], B1[6][2];
  auto LOADB = [&](v8bf (&B)[6][2], int tt) {
#pragma unroll
    for (int n = 0; n < 6; ++n)
#pragma unroll
      for (int kk = 0; kk < 2; ++kk)
        B[n][kk] = *(const v8bf*)(bb + (size_t)((wn4 * 6 + n) * 64 + tt * 2 + kk) * 512);
  };
  auto STAGE_A = [&](int tt, char* Ab) {
    const int k0 = tt * 64;
#pragma unroll
    for (int i = 0; i < 8; ++i) async16(Ab + i * 1024, pa[i] + k0);
  };
  auto COMPUTE = [&](const char* Ab, v8bf (&B)[6][2]) {
#pragma unroll
    for (int kk = 0; kk < 2; ++kk) {
      v8bf a[2];
#pragma unroll
      for (int m = 0; m < 2; ++m) {
        const int rl = m * 16 + lo;                // row in strip
        const int s = kk * 8 + hi * 2;
        const char* rowp = Ab + rl * 256;
        F4 a0, a1;
        a0.v = *(const f32x4*)(rowp + (((s)     ^ (rl & 7)) << 4));
        a1.v = *(const f32x4*)(rowp + (((s + 1) ^ (rl & 7)) << 4));
        U8 u;
#pragma unroll
        for (int q = 0; q < 4; ++q) {
          u.b[q]     = (__bf16)a0.f[q];
          u.b[q + 4] = (__bf16)a1.f[q];
        }
        a[m] = u.v;
      }
#pragma unroll
      for (int m = 0; m < 2; ++m)
#pragma unroll
        for (int n = 0; n < 6; ++n)
          acc[m][n] = __builtin_amdgcn_mfma_f32_16x16x32_bf16(a[m], B[n][kk], acc[m][n], 0, 0, 0);
    }
  };

  const int NT = NEMB / 64;  // 32 (even)
  STAGE_A(0, Abuf0);
  LOADB(B0, 0);
  for (int tt = 0; tt < NT; tt += 2) {
    STAGE_A(tt + 1, Abuf1);
    LOADB(B1, tt + 1);
    asm volatile("s_waitcnt vmcnt(20)" ::: "memory");  // step-tt's 20 ops landed
    __builtin_amdgcn_sched_barrier(0);
    COMPUTE(Abuf0, B0);
    if (tt + 2 < NT) {
      STAGE_A(tt + 2, Abuf0);
      LOADB(B0, tt + 2);
      asm volatile("s_waitcnt vmcnt(20)" ::: "memory");
    } else {
      asm volatile("s_waitcnt vmcnt(0)" ::: "memory");
    }
    __builtin_amdgcn_sched_barrier(0);
    COMPUTE(Abuf1, B1);
  }

  // epilogue: per-frag projection select (16-col frags never cross proj edge)
#pragma unroll
  for (int n = 0; n < 6; ++n) {
    const int rrb = wn4 * 96 + n * 16;      // 0..368, multiple of 16
    const int pj = rrb >> 7;
    const int col = (rrb & 127) + lo;
    __bf16* __restrict__ Out = pj == 0 ? Qb : pj == 1 ? Kb : Vb;
    const float* __restrict__ bias = pj == 0 ? bq : pj == 1 ? bk : bv;
    const float bi = bias[col];
#pragma unroll
    for (int m = 0; m < 2; ++m) {
#pragma unroll
      for (int r = 0; r < 4; ++r) {
        const int row = m0 + wm * 32 + m * 16 + hi * 4 + r;
        Out[(size_t)row * HD + col] = (__bf16)(acc[m][n][r] + bi);
      }
    }
  }
}

// ---------------- Flash attention, split-KV x4 ----------------
// grid: 8 batches * 32 q-tiles * 4 kv-chunks = 1024 blocks, 256 thr.
__global__ __launch_bounds__(256) void attn_kernel(
    const __bf16* __restrict__ Qb, const __bf16* __restrict__ Kb,
    const __bf16* __restrict__ Vb, __bf16* __restrict__ Opart,
    float* __restrict__ Ml)
{
  const int bid0 = blockIdx.x;
  const int bid = ((bid0 & 7) << 7) + (bid0 >> 3);   // one batch per XCD
  const int b = bid >> 7;
  const int q = bid & 127;
  const int qt = q >> 2;
  const int s  = q & 3;
  const int q0 = qt * 64;
  const int kv_beg = (s * (qt + 1)) >> 2;
  const int kv_end = ((s + 1) * (qt + 1)) >> 2;
  const int nst = kv_end - kv_beg;

  const int t = threadIdx.x, lane = t & 63, w = t >> 6;
  const int hi = lane >> 4, lo = lane & 15;

  __shared__ __bf16 Ksm[2][64 * 128];   // [key][d], 256B rows, swizzled
  __shared__ __bf16 Vtsm[2][128 * 64];  // [d][key], 128B rows, swizzled
  __shared__ __bf16 Psm[4][16 * 64];    // per-wave P, swizzled

  v8bf aQ[4];
  {
    const __bf16* qp = Qb + ((size_t)(b * SEQ + q0 + w * 16 + lo)) * HD + hi * 8;
#pragma unroll
    for (int kk = 0; kk < 4; ++kk) aQ[kk] = *(const v8bf*)(qp + kk * 32);
  }

  const __bf16* kga[4];
#pragma unroll
  for (int i = 0; i < 4; ++i) {
    const int r = (w * 4 + i) * 4 + (lane >> 4);   // key row 0..63
    const int c = (lane & 15) ^ (r & 7);           // 16B chunk within 256B row
    kga[i] = Kb + ((size_t)(b * SEQ) + r) * HD + c * 8;
  }

  const int keyg = t >> 4, dg = t & 15;   // keys keyg*4.., d-cols dg*8..
  U8 vv[4];

  f32x4 accO[8];
  const f32x4 fz = {0.f, 0.f, 0.f, 0.f};
#pragma unroll
  for (int n = 0; n < 8; ++n) accO[n] = fz;
  float m_s[4], l_s[4];
#pragma unroll
  for (int r = 0; r < 4; ++r) { m_s[r] = -INFINITY; l_s[r] = 0.f; }

  const float scale = 0.022097086912079608f;  // 1/sqrt(2048)

  if (nst > 0) {
    auto STAGE_K = [&](int kv, int buf) {
      const size_t off = (size_t)kv * 64 * HD;
      char* kb = (char*)&Ksm[buf][0];
#pragma unroll
      for (int i = 0; i < 4; ++i) async16(kb + (w * 4 + i) * 1024, kga[i] + off);
    };
    auto LOAD_V = [&](int kv) {
      const __bf16* vp = Vb + ((size_t)(b * SEQ + kv * 64 + keyg * 4)) * HD + dg * 8;
#pragma unroll
      for (int j = 0; j < 4; ++j) vv[j].v = *(const v8bf*)(vp + (size_t)j * HD);
    };
    auto WRITE_VT = [&](int buf) {
      char* vb2 = (char*)&Vtsm[buf][0];
#pragma unroll
      for (int dd = 0; dd < 8; ++dd) {
        const int d = (dd + dg) & 7;               // rotation: row&7 spans lanes
        ushort4 pk = make_ushort4(vv[0].e[d], vv[1].e[d], vv[2].e[d], vv[3].e[d]);
        const int row = dg * 8 + d;
        *(ushort4*)(vb2 + row * 128 + ((keyg * 8) ^ ((row & 7) << 4))) = pk;
      }
    };

    STAGE_K(kv_beg, 0);
    LOAD_V(kv_beg);
    WRITE_VT(0);
    __syncthreads();   // K DMA drained + Vt visible

    for (int t2 = 0; t2 < nst; ++t2) {
      const int kv = kv_beg + t2;
      const int cur = t2 & 1;
      const bool more = (t2 + 1 < nst);
      if (more) { STAGE_K(kv + 1, cur ^ 1); LOAD_V(kv + 1); }

      // S = Q K^T
      f32x4 accS[4];
#pragma unroll
      for (int n = 0; n < 4; ++n) accS[n] = fz;
      const char* ksm = (const char*)&Ksm[cur][0];
#pragma unroll
      for (int kk = 0; kk < 4; ++kk) {
        const int cb = kk * 64 + hi * 16;
        v8bf bk[4];
#pragma unroll
        for (int n = 0; n < 4; ++n) {
          const int r = n * 16 + lo;
          bk[n] = *(const v8bf*)(ksm + r * 256 + (cb ^ ((r & 7) << 4)));
        }
#pragma unroll
        for (int n = 0; n < 4; ++n)
          accS[n] = __builtin_amdgcn_mfma_f32_16x16x32_bf16(aQ[kk], bk[n], accS[n], 0, 0, 0);
      }

      float sv[4][4];
      const bool diag = (kv == qt);
#pragma unroll
      for (int n = 0; n < 4; ++n)
#pragma unroll
        for (int r = 0; r < 4; ++r) {
          float v = accS[n][r] * scale;
          if (diag) {
            const int key = kv * 64 + n * 16 + lo;
            const int qr = q0 + w * 16 + hi * 4 + r;
            if (key > qr) v = -INFINITY;
          }
          sv[n][r] = v;
        }

      float mx[4];
#pragma unroll
      for (int r = 0; r < 4; ++r) {
        mx[r] = fmaxf(fmaxf(sv[0][r], sv[1][r]), fmaxf(sv[2][r], sv[3][r]));
#pragma unroll
        for (int off = 1; off < 16; off <<= 1)
          mx[r] = fmaxf(mx[r], __shfl_xor(mx[r], off));
      }
      float corr[4], p[4][4], rs[4];
#pragma unroll
      for (int r = 0; r < 4; ++r) {
        const float mnew = fmaxf(m_s[r], mx[r]);
        corr[r] = __expf(m_s[r] - mnew);
        m_s[r] = mnew;
        rs[r] = 0.f;
      }
#pragma unroll
      for (int n = 0; n < 4; ++n)
#pragma unroll
        for (int r = 0; r < 4; ++r) {
          p[n][r] = __expf(sv[n][r] - m_s[r]);
          rs[r] += p[n][r];
        }
#pragma unroll
      for (int r = 0; r < 4; ++r) {
#pragma unroll
        for (int off = 1; off < 16; off <<= 1) rs[r] += __shfl_xor(rs[r], off);
        l_s[r] = l_s[r] * corr[r] + rs[r];
      }
#pragma unroll
      for (int n = 0; n < 8; ++n)
#pragma unroll
        for (int r = 0; r < 4; ++r) accO[n][r] *= corr[r];

#pragma unroll
      for (int n = 0; n < 4; ++n)
#pragma unroll
        for (int r = 0; r < 4; ++r) {
          const int row = hi * 4 + r;
          __bf16 h = (__bf16)p[n][r];
          *(unsigned short*)((char*)&Psm[w][0] + row * 128 +
                             (((n * 16 + lo) * 2) ^ ((row & 7) << 4))) =
              __builtin_bit_cast(unsigned short, h);
        }

      if (more) WRITE_VT(cur ^ 1);

      const char* vsm = (const char*)&Vtsm[cur][0];
#pragma unroll
      for (int k2 = 0; k2 < 2; ++k2) {
        const int cb = k2 * 64 + hi * 16;
        const v8bf aP = *(const v8bf*)((const char*)&Psm[w][0] + lo * 128 + (cb ^ ((lo & 7) << 4)));
#pragma unroll
        for (int n = 0; n < 8; ++n) {
          const int r = n * 16 + lo;
          const v8bf bv = *(const v8bf*)(vsm + r * 128 + (cb ^ ((r & 7) << 4)));
          accO[n] = __builtin_amdgcn_mfma_f32_16x16x32_bf16(aP, bv, accO[n], 0, 0, 0);
        }
      }
      if (more) __syncthreads();
    }
  }

  // store partials: unnormalized O (bf16), m, l
#pragma unroll
  for (int r = 0; r < 4; ++r) {
    const int qr = q0 + w * 16 + hi * 4 + r;
    __bf16* op = Opart + ((size_t)s * NROWS + b * SEQ + qr) * HD + lo;
#pragma unroll
    for (int n = 0; n < 8; ++n) op[n * 16] = (__bf16)accO[n][r];
    if (lo == 0) {
      float* mlp = Ml + ((size_t)s * NROWS + b * SEQ + qr) * 2;
      mlp[0] = m_s[r];
      mlp[1] = l_s[r];
    }
  }
}

// ---------------- combine the four KV-chunk partials ----------------
__global__ __launch_bounds__(256) void combine_kernel(
    const __bf16* __restrict__ Opart, const float* __restrict__ Ml,
    float* __restrict__ out)
{
  const int idx = blockIdx.x * 256 + threadIdx.x;  // 0..65535
  const int row = idx >> 2, ch = idx & 3;          // 32-col chunk
  float m[4], l[4];
#pragma unroll
  for (int s = 0; s < 4; ++s) {
    const float* mlp = Ml + ((size_t)s * NROWS + row) * 2;
    m[s] = mlp[0];
    l[s] = mlp[1];
  }
  const float M = fmaxf(fmaxf(m[0], m[1]), fmaxf(m[2], m[3]));
  float e[4], denom = 0.f;
#pragma unroll
  for (int s = 0; s < 4; ++s) { e[s] = __expf(m[s] - M); denom += l[s] * e[s]; }
  const float inv = 1.f / denom;

  float* po = out + (size_t)row * HD + ch * 32;
#pragma unroll
  for (int j = 0; j < 4; ++j) {     // 4 groups of 8 cols
    float sum[8];
#pragma unroll
    for (int q2 = 0; q2 < 8; ++q2) sum[q2] = 0.f;
#pragma unroll
    for (int s = 0; s < 4; ++s) {
      U8 o;
      o.v = *(const v8bf*)(Opart + ((size_t)s * NROWS + row) * HD + ch * 32 + j * 8);
#pragma unroll
      for (int q2 = 0; q2 < 8; ++q2) sum[q2] += (float)o.b[q2] * e[s];
    }
#pragma unroll
    for (int q2 = 0; q2 < 8; ++q2) po[j * 8 + q2] = sum[q2] * inv;
  }
}

extern "C" void kernel_launch(void* const* d_in, const int* in_sizes, int n_in,
                              void* d_out, int out_size, void* d_ws, size_t ws_size,
                              hipStream_t stream) {
  const float* x  = (const float*)d_in[0];
  const float* Wq = (const float*)d_in[1];
  const float* bq = (const float*)d_in[2];
  const float* Wk = (const float*)d_in[3];
  const float* bk = (const float*)d_in[4];
  const float* Wv = (const float*)d_in[5];
  const float* bv = (const float*)d_in[6];
  float* out = (float*)d_out;

  // workspace (~30 MiB)
  __bf16* Qb = (__bf16*)d_ws;                        // 16384x128 bf16 each
  __bf16* Kb = Qb + (size_t)NROWS * HD;
  __bf16* Vb = Kb + (size_t)NROWS * HD;
  __bf16* Wp = Vb + (size_t)NROWS * HD;              // 1536 x 512 bf16 = 1.5 MB
  __bf16* Opart = Wp + (size_t)1536 * 512;           // 4 x 16384 x 128 bf16
  float*  Ml = (float*)(Opart + (size_t)4 * NROWS * HD);  // 4 x 16384 x 2 fp32

  wpack_kernel<<<dim3(384), dim3(256), 0, stream>>>(Wq, Wk, Wv, Wp);
  qkv_fused_kernel<<<dim3(256), dim3(512), 0, stream>>>(
      x, Wp, bq, bk, bv, Qb, Kb, Vb);
  attn_kernel<<<dim3(BATCH * 32 * 4), dim3(256), 0, stream>>>(Qb, Kb, Vb, Opart, Ml);
  combine_kernel<<<dim3(NROWS * 4 / 256), dim3(256), 0, stream>>>(Opart, Ml, out);
}